// Round 8
// baseline (766.792 us; speedup 1.0000x reference)
//
#include <hip/hip_runtime.h>
#include <math.h>

#define NN 16500
#define NP 16512      // 129 * 128 padded rows
#define NE 100000
#define KT 3

typedef __attribute__((ext_vector_type(8))) short bf8_t;   // 8 x bf16
typedef __attribute__((ext_vector_type(4))) float f4_t;    // MFMA accumulator

__device__ __forceinline__ unsigned short f2bf(float f) {
    unsigned int u = __float_as_uint(f);
    u += 0x7fffu + ((u >> 16) & 1u);   // RNE
    return (unsigned short)(u >> 16);
}
__device__ __forceinline__ float bf2f(unsigned short h) {
    return __uint_as_float(((unsigned int)h) << 16);
}
__device__ __forceinline__ void gload16(unsigned short* lds, const unsigned short* g) {
    __builtin_amdgcn_global_load_lds(
        (const __attribute__((address_space(1))) void*)g,
        (__attribute__((address_space(3))) void*)lds, 16, 0, 0);
}

// ---------------- CSR build ----------------

__global__ void deg_kernel(const int* __restrict__ ei, int* __restrict__ deg) {
    int t = blockIdx.x * blockDim.x + threadIdx.x;
    if (t >= KT * NE) return;
    int k = t / NE, e = t - k * NE;
    int d = ei[k * 2 * NE + NE + e];
    atomicAdd(&deg[k * NN + d], 1);
}

__global__ void scan_kernel(const int* __restrict__ deg, int* __restrict__ offs,
                            int* __restrict__ cursor) {
    int k = blockIdx.x;
    const int* dg = deg + k * NN;
    int* of = offs + k * (NN + 1);
    int* cu = cursor + k * NN;
    __shared__ int part[256];
    int tid = threadIdx.x;
    const int chunk = (NN + 255) / 256;
    int s0 = tid * chunk, s1 = min(NN, s0 + chunk);
    if (s0 > s1) s0 = s1;
    int sum = 0;
    for (int i = s0; i < s1; ++i) sum += dg[i];
    part[tid] = sum;
    __syncthreads();
    for (int off = 1; off < 256; off <<= 1) {
        int v = part[tid];
        int vp = (tid >= off) ? part[tid - off] : 0;
        __syncthreads();
        part[tid] = v + vp;
        __syncthreads();
    }
    int run = (tid == 0) ? 0 : part[tid - 1];
    for (int i = s0; i < s1; ++i) {
        of[i] = run; cu[i] = run;
        run += dg[i];
    }
    if (tid == 255) of[NN] = run;
}

__global__ void scatter_kernel(const int* __restrict__ ei, int* __restrict__ cursor,
                               int* __restrict__ eids) {
    int t = blockIdx.x * blockDim.x + threadIdx.x;
    if (t >= KT * NE) return;
    int k = t / NE, e = t - k * NE;
    int d = ei[k * 2 * NE + NE + e];
    int pos = atomicAdd(&cursor[k * NN + d], 1);
    eids[k * NE + pos] = e;
}

// ---------------- softmax aggregation: channel-split passes (L2-resident gathers) ----------------
// One wave per (dst, k); blockIdx.z = channel pass. Each lane owns CHPL channels, 4B gather/edge.

template<bool BF16X>
__device__ __forceinline__ void loadC(float out[2], const void* xv, int s, int c0, int ci) {
    if (BF16X) {
        unsigned int u = *(const unsigned int*)((const unsigned short*)xv + (size_t)s * ci + c0);
        out[0] = bf2f((unsigned short)(u & 0xffffu));
        out[1] = bf2f((unsigned short)(u >> 16));
    } else {
        out[0] = ((const float*)xv)[(size_t)s * ci + c0];
        out[1] = 0.f;
    }
}

template<bool BF16X>
__global__ __launch_bounds__(256) void aggr_kernel(
    const void* __restrict__ xv, const int* __restrict__ ei,
    const float* __restrict__ ea_all, const int* __restrict__ offs_all,
    const int* __restrict__ eids_all, const float* __restrict__ We_all,
    const float* __restrict__ be_all,
    unsigned short* __restrict__ out_hi, int ci, int kp)
{
    constexpr int CHPL = BF16X ? 2 : 1;
    int k = blockIdx.y;
    int wv = threadIdx.x >> 6, lane = threadIdx.x & 63;
    int d = blockIdx.x * 4 + wv;
    int c0 = blockIdx.z * 64 * CHPL + lane * CHPL;
    unsigned short* o = out_hi + (size_t)k * NP * kp;
    if (d >= NN) {
        if (c0 < kp) {
            if (BF16X) *(unsigned int*)(o + (size_t)d * kp + c0) = 0u;
            else o[(size_t)d * kp + c0] = 0;
        }
        return;
    }
    const int*   src  = ei + (size_t)k * 2 * NE;
    const float* ea   = ea_all + (size_t)k * NE;
    const int*   offs = offs_all + k * (NN + 1);
    const int*   eids = eids_all + (size_t)k * NE;
    const float* We   = We_all + (size_t)k * ci;
    const float* be   = be_all + (size_t)k * ci;

    bool act = c0 < ci;
    float w[CHPL], b[CHPL], xd[2] = {0.f, 0.f};
    #pragma unroll
    for (int e = 0; e < CHPL; ++e) {
        bool a = (c0 + e) < ci;
        w[e] = a ? We[c0 + e] : 0.f;
        b[e] = a ? be[c0 + e] : 0.f;
    }
    if (act) loadC<BF16X>(xd, xv, d, c0, ci);
    #pragma unroll
    for (int e = 0; e < CHPL; ++e) if ((c0 + e) >= ci) xd[e] = 0.f;

    float m[CHPL], den[CHPL], num[CHPL];
    #pragma unroll
    for (int e = 0; e < CHPL; ++e) {
        float mg = fmaxf(xd[e] + w[e] + b[e], 0.f);   // self loop, ea=1
        m[e] = mg; den[e] = 1.f; num[e] = mg;
    }

    int start = offs[d], end = offs[d + 1];
    for (int base = start; base < end; base += 64) {
        int cnt = min(64, end - base);
        int sv = 0; float av = 0.f;
        if (lane < cnt) {
            int e2 = eids[base + lane];
            sv = src[e2];
            av = ea[e2];
        }
        float xn[2] = {0.f, 0.f};
        int s0 = __shfl(sv, 0);
        if (act) loadC<BF16X>(xn, xv, s0, c0, ci);
        for (int j = 0; j < cnt; ++j) {
            float xc[2] = {xn[0], xn[1]};
            float a = __shfl(av, j);
            if (j + 1 < cnt) {
                int sn = __shfl(sv, j + 1);
                if (act) loadC<BF16X>(xn, xv, sn, c0, ci);
            }
            #pragma unroll
            for (int e = 0; e < CHPL; ++e) {
                float t = xc[e] + fmaf(a, w[e], b[e]);
                float mg = fmaxf(t, 0.f);
                float nm = fmaxf(m[e], mg);
                float mn = fminf(m[e], mg);
                float ex = __expf(mn - nm);       // single exp per channel-edge
                bool keep = m[e] >= mg;
                float e0 = keep ? 1.f : ex;
                float e1 = keep ? ex : 1.f;
                den[e] = fmaf(den[e], e0, e1);
                num[e] = fmaf(num[e], e0, mg * e1);
                m[e] = nm;
            }
        }
    }
    if (c0 < kp) {
        unsigned short r[CHPL];
        #pragma unroll
        for (int e = 0; e < CHPL; ++e) {
            float v = ((c0 + e) < ci) ? (num[e] / den[e] + xd[e]) : 0.f;
            r[e] = f2bf(v);
        }
        if (BF16X)
            *(unsigned int*)(o + (size_t)d * kp + c0) =
                (unsigned)r[0] | ((unsigned)r[1] << 16);
        else
            o[(size_t)d * kp + c0] = r[0];
    }
}

// ---------------- weight split+transpose, all 6 jobs in one launch ----------------

struct SplitJob { const float* W; unsigned short* out; int kdim, ndim, np_, kp; };
struct SplitJobs { SplitJob j[6]; };

__global__ void split_all_kernel(SplitJobs jobs) {
    SplitJob jb = jobs.j[blockIdx.z];
    int idx = blockIdx.x * 256 + threadIdx.x;
    int total = KT * jb.np_ * jb.kp;
    if (idx >= total) return;
    int k = idx / (jb.np_ * jb.kp);
    int rem = idx - k * jb.np_ * jb.kp;
    int n = rem / jb.kp;
    int kk = rem - n * jb.kp;
    float v = (n < jb.ndim && kk < jb.kdim) ? jb.W[((size_t)k * jb.kdim + kk) * jb.ndim + n] : 0.f;
    jb.out[idx] = f2bf(v);
}

// ---------------- GEMM1: bf16 MFMA, conflict-free LDS, fused BN stats, bf16 h out ----------------

__global__ __launch_bounds__(256, 3) void gemm1_mfma(
    const unsigned short* __restrict__ A_hi,
    const unsigned short* __restrict__ B_hi,
    const float* __restrict__ bias_all, unsigned short* __restrict__ C_all,
    float* __restrict__ psum,
    int KP, int ldc, int Mv, int Nv)
{
    __shared__ unsigned short Ah[128 * 32];
    __shared__ unsigned short Bh[128 * 32];

    int z = blockIdx.z;
    int gxT = gridDim.x, gyT = gridDim.y;
    int NHP = gxT * 128;
    const unsigned short* Ahg = A_hi + (size_t)z * NP * KP;
    const unsigned short* Bhg = B_hi + (size_t)z * NHP * KP;
    const float* bias = bias_all + (size_t)z * Nv;
    unsigned short* C = C_all + (size_t)z * NP * ldc;

    int tid = threadIdx.x;
    int w = tid >> 6, l = tid & 63;
    int bm = blockIdx.y * 128, bn = blockIdx.x * 128;
    int lane15 = l & 15, quad = l >> 4;
    int wm = (w >> 1) * 64, wn = (w & 1) * 64;
    int srow = l & 15;
    int scol = (l >> 4) * 8;

    f4_t acc[4][4];
    #pragma unroll
    for (int i = 0; i < 4; ++i)
        #pragma unroll
        for (int j = 0; j < 4; ++j) { f4_t zz = {0.f,0.f,0.f,0.f}; acc[i][j] = zz; }

    size_t aoff0 = (size_t)(bm + 32 * w +  0 + srow) * KP + scol;
    size_t aoff1 = (size_t)(bm + 32 * w + 16 + srow) * KP + scol;
    size_t boff0 = (size_t)(bn + 32 * w +  0 + srow) * KP + scol;
    size_t boff1 = (size_t)(bn + 32 * w + 16 + srow) * KP + scol;
    int rb0 = 32 * w, rb1 = 32 * w + 16;
    int ta = (w >> 1) * 4, tb = (w & 1) * 4;

    for (int k0 = 0; k0 < KP; k0 += 32) {
        gload16(&Ah[rb0 * 32], Ahg + aoff0 + k0);
        gload16(&Ah[rb1 * 32], Ahg + aoff1 + k0);
        gload16(&Bh[rb0 * 32], Bhg + boff0 + k0);
        gload16(&Bh[rb1 * 32], Bhg + boff1 + k0);
        __syncthreads();

        bf8_t fa[4], fb[4];
        #pragma unroll
        for (int i = 0; i < 4; ++i) {
            fa[i] = *(const bf8_t*)&Ah[(ta + i) * 512 + l * 8];
            fb[i] = *(const bf8_t*)&Bh[(tb + i) * 512 + l * 8];
        }
        #pragma unroll
        for (int i = 0; i < 4; ++i)
            #pragma unroll
            for (int j = 0; j < 4; ++j)
                acc[i][j] = __builtin_amdgcn_mfma_f32_16x16x32_bf16(fa[i], fb[j], acc[i][j], 0, 0, 0);
        __syncthreads();
    }

    // epilogue: bf16 C write + fused BN partial stats (on quantized values)
    #pragma unroll
    for (int j = 0; j < 4; ++j) {
        int c = bn + wn + j * 16 + lane15;
        float bc = (c < Nv) ? bias[c] : 0.f;
        float s1 = 0.f, s2 = 0.f;
        #pragma unroll
        for (int i = 0; i < 4; ++i) {
            #pragma unroll
            for (int r5 = 0; r5 < 4; ++r5) {
                int r = bm + wm + i * 16 + quad * 4 + r5;
                float v = acc[i][j][r5] + bc;
                unsigned short q = f2bf(v);
                if (r < Mv && c < Nv) C[(size_t)r * ldc + c] = q;
                bool ok = (r < NN) && (c < Nv);
                float vq = ok ? bf2f(q) : 0.f;
                s1 += vq;
                s2 = fmaf(vq, vq, s2);
            }
        }
        s1 += __shfl_xor(s1, 16); s2 += __shfl_xor(s2, 16);
        s1 += __shfl_xor(s1, 32); s2 += __shfl_xor(s2, 32);
        if (quad == 0) {
            int wrow = w >> 1;
            int col = wn + j * 16 + lane15;
            size_t o = ((((size_t)z * gyT + blockIdx.y) * gxT + blockIdx.x) * 2 + wrow) * 256 + col * 2;
            float2 st = {s1, s2};
            *(float2*)&psum[o] = st;
        }
    }
}

// ---------------- finalize BN scale/shift from partials ----------------

__global__ __launch_bounds__(512) void finalize_kernel(
    const float* __restrict__ psum,
    const float* __restrict__ g_all, const float* __restrict__ bt_all,
    float* __restrict__ scale_all, float* __restrict__ shift_all,
    int hid, int gxT)
{
    int z = blockIdx.x;
    int c = threadIdx.x;
    if (c >= hid) return;
    int gx = c >> 7, col = c & 127;
    double s1 = 0.0, s2 = 0.0;
    for (int gy = 0; gy < NP / 128; ++gy) {
        size_t base = (((size_t)z * (NP / 128) + gy) * gxT + gx) * 2 * 256 + col * 2;
        float2 a  = *(const float2*)&psum[base];
        float2 b2 = *(const float2*)&psum[base + 256];
        s1 += (double)a.x + b2.x;
        s2 += (double)a.y + b2.y;
    }
    double mu = s1 / NN;
    double var = s2 / NN - mu * mu;
    if (var < 0.0) var = 0.0;
    float rs = (float)(1.0 / sqrt(var + 1e-5));
    float sc = rs * g_all[(size_t)z * hid + c];
    scale_all[(size_t)z * 512 + c] = sc;
    shift_all[(size_t)z * 512 + c] = bt_all[(size_t)z * hid + c] - (float)mu * sc;
}

// ---------------- GEMM2: z in grid, 128x128 tiles, fused BN+ReLU A-stage (bf16 h), partial out ----------------

__global__ __launch_bounds__(256, 3) void gemm2_mfma(
    const unsigned short* __restrict__ h_all, const float* __restrict__ scale_all,
    const float* __restrict__ shift_all,
    const unsigned short* __restrict__ B_hi,
    float* __restrict__ P_all, int KP, int hid, int Mv)
{
    __shared__ unsigned short Ah[128 * 32];
    __shared__ unsigned short Bh[128 * 32];

    int z = blockIdx.z;
    const unsigned short* hz = h_all + (size_t)z * NP * KP;
    const float* scl = scale_all + (size_t)z * 512;
    const float* shf = shift_all + (size_t)z * 512;
    const unsigned short* Bhg = B_hi + (size_t)z * 256 * KP;
    float* P = P_all + (size_t)z * NP * 256;

    int tid = threadIdx.x;
    int w = tid >> 6, l = tid & 63;
    int bm = blockIdx.y * 128, bn = blockIdx.x * 128;
    int lane15 = l & 15, quad = l >> 4;
    int wm = (w >> 1) * 64, wn = (w & 1) * 64;
    int srow = l & 15, scol = (l >> 4) * 8;

    f4_t acc[4][4];
    #pragma unroll
    for (int i = 0; i < 4; ++i)
        #pragma unroll
        for (int j = 0; j < 4; ++j) { f4_t zz = {0.f,0.f,0.f,0.f}; acc[i][j] = zz; }

    size_t boff0 = (size_t)(bn + 32 * w +  0 + srow) * KP + scol;
    size_t boff1 = (size_t)(bn + 32 * w + 16 + srow) * KP + scol;
    int rb0 = 32 * w, rb1 = 32 * w + 16;
    int ta = (w >> 1) * 4, tb = (w & 1) * 4;

    for (int k0 = 0; k0 < KP; k0 += 32) {
        gload16(&Bh[rb0 * 32], Bhg + boff0 + k0);
        gload16(&Bh[rb1 * 32], Bhg + boff1 + k0);

        // BN+ReLU A-stage from bf16 h, fragment-major (thread L owns LDS bytes L*16)
        #pragma unroll
        for (int sseg = 0; sseg < 2; ++sseg) {
            int L = sseg * 256 + tid;
            int chunk = (L >> 4) & 3;
            int grow = ((L >> 6) << 4) + (L & 15);
            int c = k0 + chunk * 8;
            uint4 hv = *(const uint4*)(hz + (size_t)(bm + grow) * KP + c);
            float4 s0 = *(const float4*)(scl + c);
            float4 s1 = *(const float4*)(scl + c + 4);
            float4 t0 = *(const float4*)(shf + c);
            float4 t1 = *(const float4*)(shf + c + 4);
            unsigned int uu[4] = {hv.x, hv.y, hv.z, hv.w};
            float ss[8] = {s0.x, s0.y, s0.z, s0.w, s1.x, s1.y, s1.z, s1.w};
            float tt[8] = {t0.x, t0.y, t0.z, t0.w, t1.x, t1.y, t1.z, t1.w};
            bf8_t hi8;
            #pragma unroll
            for (int e = 0; e < 8; ++e) {
                unsigned short hb = (e & 1) ? (unsigned short)(uu[e >> 1] >> 16)
                                            : (unsigned short)(uu[e >> 1] & 0xffffu);
                float x = bf2f(hb);
                float val = (c + e < hid) ? fmaxf(fmaf(x, ss[e], tt[e]), 0.f) : 0.f;
                hi8[e] = (short)f2bf(val);
            }
            *(bf8_t*)&Ah[L * 8] = hi8;
        }
        __syncthreads();

        bf8_t fa[4], fb[4];
        #pragma unroll
        for (int i = 0; i < 4; ++i) {
            fa[i] = *(const bf8_t*)&Ah[(ta + i) * 512 + l * 8];
            fb[i] = *(const bf8_t*)&Bh[(tb + i) * 512 + l * 8];
        }
        #pragma unroll
        for (int i = 0; i < 4; ++i)
            #pragma unroll
            for (int j = 0; j < 4; ++j)
                acc[i][j] = __builtin_amdgcn_mfma_f32_16x16x32_bf16(fa[i], fb[j], acc[i][j], 0, 0, 0);
        __syncthreads();
    }

    #pragma unroll
    for (int i = 0; i < 4; ++i)
        #pragma unroll
        for (int j = 0; j < 4; ++j) {
            int c = bn + wn + j * 16 + lane15;
            #pragma unroll
            for (int r5 = 0; r5 < 4; ++r5) {
                int r = bm + wm + i * 16 + quad * 4 + r5;
                if (r < Mv)
                    P[(size_t)r * 256 + c] = acc[i][j][r5];
            }
        }
}

// ---------------- reduce over k + Σbias + leaky; out fp32 or bf16 ----------------

__global__ __launch_bounds__(256) void reduce_kernel(
    const float* __restrict__ P, const float* __restrict__ bb,
    float* __restrict__ outf, unsigned short* __restrict__ outb,
    int leaky, int as_bf16)
{
    int idx = blockIdx.x * 256 + threadIdx.x;
    if (idx >= NN * 64) return;
    int r = idx >> 6, c = (idx & 63) * 4;
    const float4 p0 = *(const float4*)&P[((size_t)0 * NP + r) * 256 + c];
    const float4 p1 = *(const float4*)&P[((size_t)1 * NP + r) * 256 + c];
    const float4 p2 = *(const float4*)&P[((size_t)2 * NP + r) * 256 + c];
    const float4 b0 = *(const float4*)&bb[c];
    const float4 b1 = *(const float4*)&bb[256 + c];
    const float4 b2 = *(const float4*)&bb[512 + c];
    float v[4] = {p0.x + p1.x + p2.x + b0.x + b1.x + b2.x,
                  p0.y + p1.y + p2.y + b0.y + b1.y + b2.y,
                  p0.z + p1.z + p2.z + b0.z + b1.z + b2.z,
                  p0.w + p1.w + p2.w + b0.w + b1.w + b2.w};
    if (leaky) {
        #pragma unroll
        for (int e = 0; e < 4; ++e) v[e] = (v[e] > 0.f) ? v[e] : 0.01f * v[e];
    }
    if (as_bf16) {
        unsigned int o0 = (unsigned int)f2bf(v[0]) | ((unsigned int)f2bf(v[1]) << 16);
        unsigned int o1 = (unsigned int)f2bf(v[2]) | ((unsigned int)f2bf(v[3]) << 16);
        uint2 o = {o0, o1};
        *(uint2*)&outb[(size_t)r * 256 + c] = o;
    } else {
        float4 o = {v[0], v[1], v[2], v[3]};
        *(float4*)&outf[(size_t)r * 256 + c] = o;
    }
}

// ---------------- host ----------------

extern "C" void kernel_launch(void* const* d_in, const int* in_sizes, int n_in,
                              void* d_out, int out_size, void* d_ws, size_t ws_size,
                              hipStream_t stream)
{
    const float* x  = (const float*)d_in[0];
    const int*   ei = (const int*)d_in[1];
    const float* ea = (const float*)d_in[2];

    char* w = (char*)d_ws;
    auto alloc = [&](size_t bytes) {
        char* p = w;
        w += (bytes + 255) & ~(size_t)255;
        return p;
    };
    int* deg    = (int*)alloc((size_t)KT * NN * 4);
    int* offs   = (int*)alloc((size_t)KT * (NN + 1) * 4);
    int* cursor = (int*)alloc((size_t)KT * NN * 4);
    int* eids   = (int*)alloc((size_t)KT * NE * 4);
    unsigned short* a1_hi = (unsigned short*)alloc((size_t)KT * NP * 256 * 2);
    unsigned short* h3 = (unsigned short*)alloc((size_t)KT * NP * 512 * 2);
    float* partial = (float*)alloc((size_t)KT * NP * 256 * 4);
    unsigned short* bta_l[3];
    unsigned short* btb_l[3];
    for (int l = 0; l < 3; ++l) {
        bta_l[l] = (unsigned short*)alloc((size_t)KT * 512 * 256 * 2);
        btb_l[l] = (unsigned short*)alloc((size_t)KT * 256 * 512 * 2);
    }
    float* psum = (float*)alloc((size_t)KT * (NP / 128) * 4 * 2 * 256 * 4);
    float* scale3 = (float*)alloc((size_t)KT * 512 * 4);
    float* shift3 = (float*)alloc((size_t)KT * 512 * 4);
    unsigned short* bufA = (unsigned short*)alloc((size_t)NN * 256 * 2);
    unsigned short* bufB = (unsigned short*)alloc((size_t)NN * 256 * 2);

    hipMemsetAsync(deg, 0, (size_t)KT * NN * 4, stream);
    int net = KT * NE;
    deg_kernel<<<(net + 255) / 256, 256, 0, stream>>>(ei, deg);
    scan_kernel<<<KT, 256, 0, stream>>>(deg, offs, cursor);
    scatter_kernel<<<(net + 255) / 256, 256, 0, stream>>>(ei, cursor, eids);

    SplitJobs jobs;
    int maxtot = 0;
    for (int l = 0; l < 3; ++l) {
        int ci  = (l == 0) ? 170 : 256;
        int KP1 = (ci + 31) / 32 * 32;
        int hid = 2 * ci;
        int NHP = (hid + 127) / 128 * 128;
        int KP2 = (hid + 31) / 32 * 32;
        jobs.j[2 * l]     = { (const float*)d_in[3 + 8 * l + 2], bta_l[l], ci,  hid, NHP, KP1 };
        jobs.j[2 * l + 1] = { (const float*)d_in[3 + 8 * l + 6], btb_l[l], hid, 256, 256, KP2 };
        maxtot = max(maxtot, KT * NHP * KP1);
        maxtot = max(maxtot, KT * 256 * KP2);
    }
    dim3 gsp((maxtot + 255) / 256, 1, 6);
    split_all_kernel<<<gsp, 256, 0, stream>>>(jobs);

    const void* hin = x;
    for (int l = 0; l < 3; ++l) {
        int ci  = (l == 0) ? 170 : 256;
        int KP1 = (ci + 31) / 32 * 32;        // 192 / 256
        int hid = 2 * ci;                     // 340 / 512
        int NHP = (hid + 127) / 128 * 128;    // 384 / 512
        int KP2 = (hid + 31) / 32 * 32;       // 352 / 512
        const float* We = (const float*)d_in[3 + 8 * l + 0];
        const float* be = (const float*)d_in[3 + 8 * l + 1];
        const float* ba = (const float*)d_in[3 + 8 * l + 3];
        const float* g  = (const float*)d_in[3 + 8 * l + 4];
        const float* bt = (const float*)d_in[3 + 8 * l + 5];
        const float* bb = (const float*)d_in[3 + 8 * l + 7];

        // channel-split passes: fp32 layer0 -> 3 passes x 64ch; bf16 -> 2 passes x 128ch
        if (l == 0) {
            dim3 ga(NP / 4, KT, 3);
            aggr_kernel<false><<<ga, 256, 0, stream>>>(hin, ei, ea, offs, eids, We, be,
                                                       a1_hi, ci, KP1);
        } else {
            dim3 ga(NP / 4, KT, 2);
            aggr_kernel<true><<<ga, 256, 0, stream>>>(hin, ei, ea, offs, eids, We, be,
                                                      a1_hi, ci, KP1);
        }

        dim3 g1(NHP / 128, NP / 128, KT);
        gemm1_mfma<<<g1, 256, 0, stream>>>(a1_hi, bta_l[l], ba, h3, psum, KP1, KP2, NN, hid);

        finalize_kernel<<<KT, 512, 0, stream>>>(psum, g, bt, scale3, shift3, hid, NHP / 128);

        dim3 g2(2, NP / 128, KT);
        gemm2_mfma<<<g2, 256, 0, stream>>>(h3, scale3, shift3, btb_l[l],
                                           partial, KP2, hid, NP);

        unsigned short* outb = (l == 0) ? bufA : bufB;
        reduce_kernel<<<(NN * 64 + 255) / 256, 256, 0, stream>>>(
            partial, bb, (float*)d_out, outb, (l < 2) ? 1 : 0, (l < 2) ? 1 : 0);

        hin = (l < 2) ? (const void*)outb : nullptr;
    }
}

// Round 9
// 697.946 us; speedup vs baseline: 1.0986x; 1.0986x over previous
//
#include <hip/hip_runtime.h>
#include <math.h>

#define NN 16500
#define NP 16512      // 129 * 128 padded rows
#define NE 100000
#define KT 3

typedef __attribute__((ext_vector_type(8))) short bf8_t;   // 8 x bf16
typedef __attribute__((ext_vector_type(4))) float f4_t;    // MFMA accumulator

__device__ __forceinline__ unsigned short f2bf(float f) {
    unsigned int u = __float_as_uint(f);
    u += 0x7fffu + ((u >> 16) & 1u);   // RNE
    return (unsigned short)(u >> 16);
}
__device__ __forceinline__ float bf2f(unsigned short h) {
    return __uint_as_float(((unsigned int)h) << 16);
}
__device__ __forceinline__ void gload16(unsigned short* lds, const unsigned short* g) {
    __builtin_amdgcn_global_load_lds(
        (const __attribute__((address_space(1))) void*)g,
        (__attribute__((address_space(3))) void*)lds, 16, 0, 0);
}

// ---------------- CSR build ----------------

__global__ void deg_kernel(const int* __restrict__ ei, int* __restrict__ deg) {
    int t = blockIdx.x * blockDim.x + threadIdx.x;
    if (t >= KT * NE) return;
    int k = t / NE, e = t - k * NE;
    int d = ei[k * 2 * NE + NE + e];
    atomicAdd(&deg[k * NN + d], 1);
}

__global__ void scan_kernel(const int* __restrict__ deg, int* __restrict__ offs,
                            int* __restrict__ cursor) {
    int k = blockIdx.x;
    const int* dg = deg + k * NN;
    int* of = offs + k * (NN + 1);
    int* cu = cursor + k * NN;
    __shared__ int part[256];
    int tid = threadIdx.x;
    const int chunk = (NN + 255) / 256;
    int s0 = tid * chunk, s1 = min(NN, s0 + chunk);
    if (s0 > s1) s0 = s1;
    int sum = 0;
    for (int i = s0; i < s1; ++i) sum += dg[i];
    part[tid] = sum;
    __syncthreads();
    for (int off = 1; off < 256; off <<= 1) {
        int v = part[tid];
        int vp = (tid >= off) ? part[tid - off] : 0;
        __syncthreads();
        part[tid] = v + vp;
        __syncthreads();
    }
    int run = (tid == 0) ? 0 : part[tid - 1];
    for (int i = s0; i < s1; ++i) {
        of[i] = run; cu[i] = run;
        run += dg[i];
    }
    if (tid == 255) of[NN] = run;
}

__global__ void scatter_kernel(const int* __restrict__ ei, int* __restrict__ cursor,
                               int* __restrict__ eids) {
    int t = blockIdx.x * blockDim.x + threadIdx.x;
    if (t >= KT * NE) return;
    int k = t / NE, e = t - k * NE;
    int d = ei[k * 2 * NE + NE + e];
    int pos = atomicAdd(&cursor[k * NN + d], 1);
    eids[k * NE + pos] = e;
}

// ---------------- softmax aggregation: one wave per (dst,k), depth-2 pipeline ----------------

template<int CI, bool BF16X>
__device__ __forceinline__ void loadrow4(float out[4], const void* xv, int s, int c0) {
    if (BF16X) {
        const unsigned short* xb = (const unsigned short*)xv;
        uint2 u = *(const uint2*)(xb + (size_t)s * CI + c0);
        out[0] = bf2f((unsigned short)(u.x & 0xffffu));
        out[1] = bf2f((unsigned short)(u.x >> 16));
        out[2] = bf2f((unsigned short)(u.y & 0xffffu));
        out[3] = bf2f((unsigned short)(u.y >> 16));
    } else {
        const float* p = (const float*)xv + (size_t)s * CI + c0;
        if (c0 + 4 <= CI) {
            float2 ab = *(const float2*)p;
            float2 cd = *(const float2*)(p + 2);
            out[0] = ab.x; out[1] = ab.y; out[2] = cd.x; out[3] = cd.y;
        } else {
            #pragma unroll
            for (int e = 0; e < 4; ++e) out[e] = (c0 + e < CI) ? p[e] : 0.f;
        }
    }
}

template<int CI, bool BF16X>
__global__ __launch_bounds__(256) void aggr_kernel(
    const void* __restrict__ xv, const int* __restrict__ ei,
    const float* __restrict__ ea_all, const int* __restrict__ offs_all,
    const int* __restrict__ eids_all, const float* __restrict__ We_all,
    const float* __restrict__ be_all,
    unsigned short* __restrict__ out_hi)
{
    constexpr int KP = (CI + 31) / 32 * 32;
    int k = blockIdx.y;
    int wv = threadIdx.x >> 6, lane = threadIdx.x & 63;
    int d = blockIdx.x * 4 + wv;
    int c0 = lane * 4;
    unsigned short* o = out_hi + (size_t)k * NP * KP;
    if (d >= NN) {
        if (c0 < KP) { uint2 z = {0u, 0u}; *(uint2*)(o + (size_t)d * KP + c0) = z; }
        return;
    }
    const int*   src  = ei + (size_t)k * 2 * NE;
    const float* ea   = ea_all + (size_t)k * NE;
    const int*   offs = offs_all + k * (NN + 1);
    const int*   eids = eids_all + (size_t)k * NE;
    const float* We   = We_all + (size_t)k * CI;
    const float* be   = be_all + (size_t)k * CI;

    constexpr bool ACT_ALL = (64 * 4 == KP) && (CI == KP);
    bool act = ACT_ALL || (c0 < CI);
    float w[4], b[4], xd[4] = {0.f, 0.f, 0.f, 0.f};
    #pragma unroll
    for (int e = 0; e < 4; ++e) {
        bool a = (c0 + e) < CI;
        w[e] = a ? We[c0 + e] : 0.f;
        b[e] = a ? be[c0 + e] : 0.f;
    }
    if (act) loadrow4<CI, BF16X>(xd, xv, d, c0);
    #pragma unroll
    for (int e = 0; e < 4; ++e) if ((c0 + e) >= CI) xd[e] = 0.f;

    float m[4], den[4], num[4];
    #pragma unroll
    for (int e = 0; e < 4; ++e) {
        float mg = fmaxf(xd[e] + w[e] + b[e], 0.f);   // self loop, ea=1
        m[e] = mg; den[e] = 1.f; num[e] = mg;
    }

    auto step = [&](const float xc[4], float a) {
        #pragma unroll
        for (int e = 0; e < 4; ++e) {
            float t = xc[e] + fmaf(a, w[e], b[e]);
            float mg = fmaxf(t, 0.f);
            float nm = fmaxf(m[e], mg);
            float mn = fminf(m[e], mg);
            float ex = __expf(mn - nm);       // single exp per channel-edge
            bool keep = m[e] >= mg;
            float e0 = keep ? 1.f : ex;
            float e1 = keep ? ex : 1.f;
            den[e] = fmaf(den[e], e0, e1);
            num[e] = fmaf(num[e], e0, mg * e1);
            m[e] = nm;
        }
    };

    int start = offs[d], end = offs[d + 1];
    for (int base = start; base < end; base += 64) {
        int cnt = min(64, end - base);
        int sv = 0; float av = 0.f;
        if (lane < cnt) {
            int e2 = eids[base + lane];
            sv = src[e2];
            av = ea[e2];
        }
        float x0[4] = {0.f,0.f,0.f,0.f}, x1[4] = {0.f,0.f,0.f,0.f};
        {
            int sA = __shfl(sv, 0);
            if (act) loadrow4<CI, BF16X>(x0, xv, sA, c0);
        }
        if (cnt > 1) {
            int sB = __shfl(sv, 1);
            if (act) loadrow4<CI, BF16X>(x1, xv, sB, c0);
        }
        int j = 0;
        for (; j + 1 < cnt; j += 2) {
            float a0 = __shfl(av, j), a1 = __shfl(av, j + 1);
            float tA[4] = {x0[0], x0[1], x0[2], x0[3]};
            float tB[4] = {x1[0], x1[1], x1[2], x1[3]};
            if (j + 2 < cnt) {
                int sn = __shfl(sv, j + 2);
                if (act) loadrow4<CI, BF16X>(x0, xv, sn, c0);
            }
            if (j + 3 < cnt) {
                int sn = __shfl(sv, j + 3);
                if (act) loadrow4<CI, BF16X>(x1, xv, sn, c0);
            }
            step(tA, a0);
            step(tB, a1);
        }
        if (j < cnt) {
            float a0 = __shfl(av, j);
            step(x0, a0);
        }
    }
    if (c0 < KP) {
        unsigned short r[4];
        #pragma unroll
        for (int e = 0; e < 4; ++e) {
            float v = ((c0 + e) < CI) ? (num[e] / den[e] + xd[e]) : 0.f;
            r[e] = f2bf(v);
        }
        uint2 pk = {(unsigned)r[0] | ((unsigned)r[1] << 16),
                    (unsigned)r[2] | ((unsigned)r[3] << 16)};
        *(uint2*)(o + (size_t)d * KP + c0) = pk;
    }
}

// ---------------- weight split+transpose, all 6 jobs in one launch ----------------

struct SplitJob { const float* W; unsigned short* out; int kdim, ndim, np_, kp; };
struct SplitJobs { SplitJob j[6]; };

__global__ void split_all_kernel(SplitJobs jobs) {
    SplitJob jb = jobs.j[blockIdx.z];
    int idx = blockIdx.x * 256 + threadIdx.x;
    int total = KT * jb.np_ * jb.kp;
    if (idx >= total) return;
    int k = idx / (jb.np_ * jb.kp);
    int rem = idx - k * jb.np_ * jb.kp;
    int n = rem / jb.kp;
    int kk = rem - n * jb.kp;
    float v = (n < jb.ndim && kk < jb.kdim) ? jb.W[((size_t)k * jb.kdim + kk) * jb.ndim + n] : 0.f;
    jb.out[idx] = f2bf(v);
}

// ---------------- GEMM1: bf16 MFMA, conflict-free LDS, fused BN stats, bf16 h out ----------------

__global__ __launch_bounds__(256, 3) void gemm1_mfma(
    const unsigned short* __restrict__ A_hi,
    const unsigned short* __restrict__ B_hi,
    const float* __restrict__ bias_all, unsigned short* __restrict__ C_all,
    float* __restrict__ psum,
    int KP, int ldc, int Mv, int Nv)
{
    __shared__ unsigned short Ah[128 * 32];
    __shared__ unsigned short Bh[128 * 32];

    int z = blockIdx.z;
    int gxT = gridDim.x, gyT = gridDim.y;
    int NHP = gxT * 128;
    const unsigned short* Ahg = A_hi + (size_t)z * NP * KP;
    const unsigned short* Bhg = B_hi + (size_t)z * NHP * KP;
    const float* bias = bias_all + (size_t)z * Nv;
    unsigned short* C = C_all + (size_t)z * NP * ldc;

    int tid = threadIdx.x;
    int w = tid >> 6, l = tid & 63;
    int bm = blockIdx.y * 128, bn = blockIdx.x * 128;
    int lane15 = l & 15, quad = l >> 4;
    int wm = (w >> 1) * 64, wn = (w & 1) * 64;
    int srow = l & 15;
    int scol = (l >> 4) * 8;

    f4_t acc[4][4];
    #pragma unroll
    for (int i = 0; i < 4; ++i)
        #pragma unroll
        for (int j = 0; j < 4; ++j) { f4_t zz = {0.f,0.f,0.f,0.f}; acc[i][j] = zz; }

    size_t aoff0 = (size_t)(bm + 32 * w +  0 + srow) * KP + scol;
    size_t aoff1 = (size_t)(bm + 32 * w + 16 + srow) * KP + scol;
    size_t boff0 = (size_t)(bn + 32 * w +  0 + srow) * KP + scol;
    size_t boff1 = (size_t)(bn + 32 * w + 16 + srow) * KP + scol;
    int rb0 = 32 * w, rb1 = 32 * w + 16;
    int ta = (w >> 1) * 4, tb = (w & 1) * 4;

    for (int k0 = 0; k0 < KP; k0 += 32) {
        gload16(&Ah[rb0 * 32], Ahg + aoff0 + k0);
        gload16(&Ah[rb1 * 32], Ahg + aoff1 + k0);
        gload16(&Bh[rb0 * 32], Bhg + boff0 + k0);
        gload16(&Bh[rb1 * 32], Bhg + boff1 + k0);
        __syncthreads();

        bf8_t fa[4], fb[4];
        #pragma unroll
        for (int i = 0; i < 4; ++i) {
            fa[i] = *(const bf8_t*)&Ah[(ta + i) * 512 + l * 8];
            fb[i] = *(const bf8_t*)&Bh[(tb + i) * 512 + l * 8];
        }
        #pragma unroll
        for (int i = 0; i < 4; ++i)
            #pragma unroll
            for (int j = 0; j < 4; ++j)
                acc[i][j] = __builtin_amdgcn_mfma_f32_16x16x32_bf16(fa[i], fb[j], acc[i][j], 0, 0, 0);
        __syncthreads();
    }

    // epilogue: bf16 C write + fused BN partial stats (on quantized values)
    #pragma unroll
    for (int j = 0; j < 4; ++j) {
        int c = bn + wn + j * 16 + lane15;
        float bc = (c < Nv) ? bias[c] : 0.f;
        float s1 = 0.f, s2 = 0.f;
        #pragma unroll
        for (int i = 0; i < 4; ++i) {
            #pragma unroll
            for (int r5 = 0; r5 < 4; ++r5) {
                int r = bm + wm + i * 16 + quad * 4 + r5;
                float v = acc[i][j][r5] + bc;
                unsigned short q = f2bf(v);
                if (r < Mv && c < Nv) C[(size_t)r * ldc + c] = q;
                bool ok = (r < NN) && (c < Nv);
                float vq = ok ? bf2f(q) : 0.f;
                s1 += vq;
                s2 = fmaf(vq, vq, s2);
            }
        }
        s1 += __shfl_xor(s1, 16); s2 += __shfl_xor(s2, 16);
        s1 += __shfl_xor(s1, 32); s2 += __shfl_xor(s2, 32);
        if (quad == 0) {
            int wrow = w >> 1;
            int col = wn + j * 16 + lane15;
            size_t o = ((((size_t)z * gyT + blockIdx.y) * gxT + blockIdx.x) * 2 + wrow) * 256 + col * 2;
            float2 st = {s1, s2};
            *(float2*)&psum[o] = st;
        }
    }
}

// ---------------- finalize BN scale/shift from partials ----------------

__global__ __launch_bounds__(512) void finalize_kernel(
    const float* __restrict__ psum,
    const float* __restrict__ g_all, const float* __restrict__ bt_all,
    float* __restrict__ scale_all, float* __restrict__ shift_all,
    int hid, int gxT)
{
    int z = blockIdx.x;
    int c = threadIdx.x;
    if (c >= hid) return;
    int gx = c >> 7, col = c & 127;
    double s1 = 0.0, s2 = 0.0;
    for (int gy = 0; gy < NP / 128; ++gy) {
        size_t base = (((size_t)z * (NP / 128) + gy) * gxT + gx) * 2 * 256 + col * 2;
        float2 a  = *(const float2*)&psum[base];
        float2 b2 = *(const float2*)&psum[base + 256];
        s1 += (double)a.x + b2.x;
        s2 += (double)a.y + b2.y;
    }
    double mu = s1 / NN;
    double var = s2 / NN - mu * mu;
    if (var < 0.0) var = 0.0;
    float rs = (float)(1.0 / sqrt(var + 1e-5));
    float sc = rs * g_all[(size_t)z * hid + c];
    scale_all[(size_t)z * 512 + c] = sc;
    shift_all[(size_t)z * 512 + c] = bt_all[(size_t)z * hid + c] - (float)mu * sc;
}

// ---------------- GEMM2: z in grid, 128x128 tiles, fused BN+ReLU A-stage (bf16 h), partial out ----------------

__global__ __launch_bounds__(256, 3) void gemm2_mfma(
    const unsigned short* __restrict__ h_all, const float* __restrict__ scale_all,
    const float* __restrict__ shift_all,
    const unsigned short* __restrict__ B_hi,
    float* __restrict__ P_all, int KP, int hid, int Mv)
{
    __shared__ unsigned short Ah[128 * 32];
    __shared__ unsigned short Bh[128 * 32];

    int z = blockIdx.z;
    const unsigned short* hz = h_all + (size_t)z * NP * KP;
    const float* scl = scale_all + (size_t)z * 512;
    const float* shf = shift_all + (size_t)z * 512;
    const unsigned short* Bhg = B_hi + (size_t)z * 256 * KP;
    float* P = P_all + (size_t)z * NP * 256;

    int tid = threadIdx.x;
    int w = tid >> 6, l = tid & 63;
    int bm = blockIdx.y * 128, bn = blockIdx.x * 128;
    int lane15 = l & 15, quad = l >> 4;
    int wm = (w >> 1) * 64, wn = (w & 1) * 64;
    int srow = l & 15, scol = (l >> 4) * 8;

    f4_t acc[4][4];
    #pragma unroll
    for (int i = 0; i < 4; ++i)
        #pragma unroll
        for (int j = 0; j < 4; ++j) { f4_t zz = {0.f,0.f,0.f,0.f}; acc[i][j] = zz; }

    size_t boff0 = (size_t)(bn + 32 * w +  0 + srow) * KP + scol;
    size_t boff1 = (size_t)(bn + 32 * w + 16 + srow) * KP + scol;
    int rb0 = 32 * w, rb1 = 32 * w + 16;
    int ta = (w >> 1) * 4, tb = (w & 1) * 4;

    for (int k0 = 0; k0 < KP; k0 += 32) {
        gload16(&Bh[rb0 * 32], Bhg + boff0 + k0);
        gload16(&Bh[rb1 * 32], Bhg + boff1 + k0);

        // BN+ReLU A-stage from bf16 h, fragment-major (thread L owns LDS bytes L*16)
        #pragma unroll
        for (int sseg = 0; sseg < 2; ++sseg) {
            int L = sseg * 256 + tid;
            int chunk = (L >> 4) & 3;
            int grow = ((L >> 6) << 4) + (L & 15);
            int c = k0 + chunk * 8;
            uint4 hv = *(const uint4*)(hz + (size_t)(bm + grow) * KP + c);
            float4 s0 = *(const float4*)(scl + c);
            float4 s1 = *(const float4*)(scl + c + 4);
            float4 t0 = *(const float4*)(shf + c);
            float4 t1 = *(const float4*)(shf + c + 4);
            unsigned int uu[4] = {hv.x, hv.y, hv.z, hv.w};
            float ss[8] = {s0.x, s0.y, s0.z, s0.w, s1.x, s1.y, s1.z, s1.w};
            float tt[8] = {t0.x, t0.y, t0.z, t0.w, t1.x, t1.y, t1.z, t1.w};
            bf8_t hi8;
            #pragma unroll
            for (int e = 0; e < 8; ++e) {
                unsigned short hb = (e & 1) ? (unsigned short)(uu[e >> 1] >> 16)
                                            : (unsigned short)(uu[e >> 1] & 0xffffu);
                float x = bf2f(hb);
                float val = (c + e < hid) ? fmaxf(fmaf(x, ss[e], tt[e]), 0.f) : 0.f;
                hi8[e] = (short)f2bf(val);
            }
            *(bf8_t*)&Ah[L * 8] = hi8;
        }
        __syncthreads();

        bf8_t fa[4], fb[4];
        #pragma unroll
        for (int i = 0; i < 4; ++i) {
            fa[i] = *(const bf8_t*)&Ah[(ta + i) * 512 + l * 8];
            fb[i] = *(const bf8_t*)&Bh[(tb + i) * 512 + l * 8];
        }
        #pragma unroll
        for (int i = 0; i < 4; ++i)
            #pragma unroll
            for (int j = 0; j < 4; ++j)
                acc[i][j] = __builtin_amdgcn_mfma_f32_16x16x32_bf16(fa[i], fb[j], acc[i][j], 0, 0, 0);
        __syncthreads();
    }

    #pragma unroll
    for (int i = 0; i < 4; ++i)
        #pragma unroll
        for (int j = 0; j < 4; ++j) {
            int c = bn + wn + j * 16 + lane15;
            #pragma unroll
            for (int r5 = 0; r5 < 4; ++r5) {
                int r = bm + wm + i * 16 + quad * 4 + r5;
                if (r < Mv)
                    P[(size_t)r * 256 + c] = acc[i][j][r5];
            }
        }
}

// ---------------- reduce over k + Σbias + leaky; out fp32 or bf16 ----------------

__global__ __launch_bounds__(256) void reduce_kernel(
    const float* __restrict__ P, const float* __restrict__ bb,
    float* __restrict__ outf, unsigned short* __restrict__ outb,
    int leaky, int as_bf16)
{
    int idx = blockIdx.x * 256 + threadIdx.x;
    if (idx >= NN * 64) return;
    int r = idx >> 6, c = (idx & 63) * 4;
    const float4 p0 = *(const float4*)&P[((size_t)0 * NP + r) * 256 + c];
    const float4 p1 = *(const float4*)&P[((size_t)1 * NP + r) * 256 + c];
    const float4 p2 = *(const float4*)&P[((size_t)2 * NP + r) * 256 + c];
    const float4 b0 = *(const float4*)&bb[c];
    const float4 b1 = *(const float4*)&bb[256 + c];
    const float4 b2 = *(const float4*)&bb[512 + c];
    float v[4] = {p0.x + p1.x + p2.x + b0.x + b1.x + b2.x,
                  p0.y + p1.y + p2.y + b0.y + b1.y + b2.y,
                  p0.z + p1.z + p2.z + b0.z + b1.z + b2.z,
                  p0.w + p1.w + p2.w + b0.w + b1.w + b2.w};
    if (leaky) {
        #pragma unroll
        for (int e = 0; e < 4; ++e) v[e] = (v[e] > 0.f) ? v[e] : 0.01f * v[e];
    }
    if (as_bf16) {
        unsigned int o0 = (unsigned int)f2bf(v[0]) | ((unsigned int)f2bf(v[1]) << 16);
        unsigned int o1 = (unsigned int)f2bf(v[2]) | ((unsigned int)f2bf(v[3]) << 16);
        uint2 o = {o0, o1};
        *(uint2*)&outb[(size_t)r * 256 + c] = o;
    } else {
        float4 o = {v[0], v[1], v[2], v[3]};
        *(float4*)&outf[(size_t)r * 256 + c] = o;
    }
}

// ---------------- host ----------------

extern "C" void kernel_launch(void* const* d_in, const int* in_sizes, int n_in,
                              void* d_out, int out_size, void* d_ws, size_t ws_size,
                              hipStream_t stream)
{
    const float* x  = (const float*)d_in[0];
    const int*   ei = (const int*)d_in[1];
    const float* ea = (const float*)d_in[2];

    char* w = (char*)d_ws;
    auto alloc = [&](size_t bytes) {
        char* p = w;
        w += (bytes + 255) & ~(size_t)255;
        return p;
    };
    int* deg    = (int*)alloc((size_t)KT * NN * 4);
    int* offs   = (int*)alloc((size_t)KT * (NN + 1) * 4);
    int* cursor = (int*)alloc((size_t)KT * NN * 4);
    int* eids   = (int*)alloc((size_t)KT * NE * 4);
    unsigned short* a1_hi = (unsigned short*)alloc((size_t)KT * NP * 256 * 2);
    unsigned short* h3 = (unsigned short*)alloc((size_t)KT * NP * 512 * 2);
    float* partial = (float*)alloc((size_t)KT * NP * 256 * 4);
    unsigned short* bta_l[3];
    unsigned short* btb_l[3];
    for (int l = 0; l < 3; ++l) {
        bta_l[l] = (unsigned short*)alloc((size_t)KT * 512 * 256 * 2);
        btb_l[l] = (unsigned short*)alloc((size_t)KT * 256 * 512 * 2);
    }
    float* psum = (float*)alloc((size_t)KT * (NP / 128) * 4 * 2 * 256 * 4);
    float* scale3 = (float*)alloc((size_t)KT * 512 * 4);
    float* shift3 = (float*)alloc((size_t)KT * 512 * 4);
    unsigned short* bufA = (unsigned short*)alloc((size_t)NN * 256 * 2);
    unsigned short* bufB = (unsigned short*)alloc((size_t)NN * 256 * 2);

    hipMemsetAsync(deg, 0, (size_t)KT * NN * 4, stream);
    int net = KT * NE;
    deg_kernel<<<(net + 255) / 256, 256, 0, stream>>>(ei, deg);
    scan_kernel<<<KT, 256, 0, stream>>>(deg, offs, cursor);
    scatter_kernel<<<(net + 255) / 256, 256, 0, stream>>>(ei, cursor, eids);

    SplitJobs jobs;
    int maxtot = 0;
    for (int l = 0; l < 3; ++l) {
        int ci  = (l == 0) ? 170 : 256;
        int KP1 = (ci + 31) / 32 * 32;
        int hid = 2 * ci;
        int NHP = (hid + 127) / 128 * 128;
        int KP2 = (hid + 31) / 32 * 32;
        jobs.j[2 * l]     = { (const float*)d_in[3 + 8 * l + 2], bta_l[l], ci,  hid, NHP, KP1 };
        jobs.j[2 * l + 1] = { (const float*)d_in[3 + 8 * l + 6], btb_l[l], hid, 256, 256, KP2 };
        maxtot = max(maxtot, KT * NHP * KP1);
        maxtot = max(maxtot, KT * 256 * KP2);
    }
    dim3 gsp((maxtot + 255) / 256, 1, 6);
    split_all_kernel<<<gsp, 256, 0, stream>>>(jobs);

    const void* hin = x;
    for (int l = 0; l < 3; ++l) {
        int ci  = (l == 0) ? 170 : 256;
        int KP1 = (ci + 31) / 32 * 32;        // 192 / 256
        int hid = 2 * ci;                     // 340 / 512
        int NHP = (hid + 127) / 128 * 128;    // 384 / 512
        int KP2 = (hid + 31) / 32 * 32;       // 352 / 512
        const float* We = (const float*)d_in[3 + 8 * l + 0];
        const float* be = (const float*)d_in[3 + 8 * l + 1];
        const float* ba = (const float*)d_in[3 + 8 * l + 3];
        const float* g  = (const float*)d_in[3 + 8 * l + 4];
        const float* bt = (const float*)d_in[3 + 8 * l + 5];
        const float* bb = (const float*)d_in[3 + 8 * l + 7];

        dim3 ga(NP / 4, KT);
        if (l == 0)
            aggr_kernel<170, false><<<ga, 256, 0, stream>>>(hin, ei, ea, offs, eids,
                                                            We, be, a1_hi);
        else
            aggr_kernel<256, true><<<ga, 256, 0, stream>>>(hin, ei, ea, offs, eids,
                                                           We, be, a1_hi);

        dim3 g1(NHP / 128, NP / 128, KT);
        gemm1_mfma<<<g1, 256, 0, stream>>>(a1_hi, bta_l[l], ba, h3, psum, KP1, KP2, NN, hid);

        finalize_kernel<<<KT, 512, 0, stream>>>(psum, g, bt, scale3, shift3, hid, NHP / 128);

        dim3 g2(2, NP / 128, KT);
        gemm2_mfma<<<g2, 256, 0, stream>>>(h3, scale3, shift3, btb_l[l],
                                           partial, KP2, hid, NP);

        unsigned short* outb = (l == 0) ? bufA : bufB;
        reduce_kernel<<<(NN * 64 + 255) / 256, 256, 0, stream>>>(
            partial, bb, (float*)d_out, outb, (l < 2) ? 1 : 0, (l < 2) ? 1 : 0);

        hin = (l < 2) ? (const void*)outb : nullptr;
    }
}